// Round 5
// baseline (95.101 us; speedup 1.0000x reference)
//
#include <hip/hip_runtime.h>

// PatchManifold: bilinear 10x downsample (align_corners=False, scale 10 ->
// frac == 0.5 exactly -> resized pixel = mean of 2x2 input block at rows
// 10i+4,10i+5 / cols 10j+4,10j+5), 16x16 pairwise patch affinity
// mean_d(exp(-(Pa-Pb)^2)), diag == 1, zero 2 smallest per row (stable
// first-index tie-break == jnp.argsort take-k).
//
// Input : d_in[0] = targets f32 [8,3,2560,2560]
// Output: d_out   = f32 [16,16]
//
// 2 dispatches:
//   K1 pm_resize <<<6144,256>>>: P_mat[16][98304] f32 -> ws; blocks 0..15
//      zero the 16KB shadow region, block 16 zeroes the last-block counter.
//   K2 pm_pairs  <<<768,256>>> : 2 threads/column (60 pairs each), 63-shfl
//      transposed butterfly, f64 device-scope atomics into 16 shadows; then
//      the textbook threadfence-reduction protocol (R4 bug: missing
//      __syncthreads BEFORE the counter increment -> last block could read
//      shadows before its own waves 1-3 landed their atomics):
//        atomics -> __syncthreads (drains vmcnt(0)) -> release fence ->
//        ACQ_REL counter inc -> broadcast -> acquire fence -> AGENT loads.

#define W_IN 2560
#define IMG_STRIDE (2560 * 2560)
#define D_TOTAL_I 98304
#define D_TOTAL 98304.0

#define NSHADOW 16
#define SLOT_STRIDE 128
#define SHADOW_BYTES (NSHADOW * SLOT_STRIDE * 8)   // 16 KiB
#define CTR_OFF_U32 (SHADOW_BYTES / 4)             // u32 index of counter
#define PMAT_OFF 65536
#define WS_NEEDED (PMAT_OFF + 16 * D_TOTAL_I * 4)

// ============================ K1: resize ============================

__global__ __launch_bounds__(256) void pm_resize(const float* __restrict__ in,
                                                 float* __restrict__ Pm,
                                                 unsigned int* __restrict__ wsu) {
    const int blk = blockIdx.x;            // img*256 + hh*4 + n   (6144 blocks)
    const int tid = threadIdx.x;

    // zero shadow accumulators (16KB) + last-block counter
    if (blk < 16) wsu[blk * 256 + tid] = 0u;
    else if (blk == 16 && tid == 0) wsu[CTR_OFF_U32] = 0u;

    const int n   = blk & 3;
    const int hh  = (blk >> 2) & 63;
    const int img = blk >> 8;
    const int m   = tid >> 6;
    const int ww  = tid & 63;

    const float* r0 = in + (size_t)img * IMG_STRIDE
                         + (size_t)(640 * n + 10 * hh + 4) * W_IN
                         + (640 * m + 10 * ww + 4);
    float2 t = *reinterpret_cast<const float2*>(r0);
    float2 u = *reinterpret_cast<const float2*>(r0 + W_IN);
    Pm[(size_t)(n * 4 + m) * D_TOTAL_I + img * 4096 + hh * 64 + ww] =
        0.25f * ((t.x + t.y) + (u.x + u.y));
}

// ============================ K2: pairs + finish ============================

__global__ __launch_bounds__(256) void pm_pairs(const float* __restrict__ Pm,
                                                double* __restrict__ acc,
                                                unsigned int* __restrict__ ctr,
                                                float* __restrict__ out) {
    const int tid  = threadIdx.x;
    const int lane = tid & 63;
    const int half = tid >> 7;                 // waves 0-1: pairs 0..59, 2-3: 60..119
    const int d    = blockIdx.x * 128 + (tid & 127);

    float P[16];
#pragma unroll
    for (int p = 0; p < 16; ++p) P[p] = Pm[p * D_TOTAL_I + d];

    float v[64];
    {
        int k = 0;
#pragma unroll
        for (int a = 0; a < 16; ++a)
#pragma unroll
            for (int b = a + 1; b < 16; ++b) {
                if (k >= half * 60 && k < half * 60 + 60) {
                    float df = P[a] - P[b];
                    v[k - half * 60] = __expf(-df * df);
                }
                ++k;
            }
    }
    v[60] = 0.0f; v[61] = 0.0f; v[62] = 0.0f; v[63] = 0.0f;

    // 6-stage transposed butterfly (verified R3): lane ends owning slot
    // bitrev6(lane), fully wave-summed.
#define PM_STAGE(K, H)                                         \
    {                                                          \
        const bool bit = (lane >> (K)) & 1;                    \
        _Pragma("unroll")                                      \
        for (int i = 0; i < (H); ++i) {                        \
            float keep = bit ? v[i + (H)] : v[i];              \
            float send = bit ? v[i] : v[i + (H)];              \
            v[i] = keep + __shfl_xor(send, 1 << (K), 64);      \
        }                                                      \
    }
    PM_STAGE(0, 32)
    PM_STAGE(1, 16)
    PM_STAGE(2, 8)
    PM_STAGE(3, 4)
    PM_STAGE(4, 2)
    PM_STAGE(5, 1)
#undef PM_STAGE

    const int r = __brev(lane) >> 26;
    double* shadow = acc + (size_t)(blockIdx.x & (NSHADOW - 1)) * SLOT_STRIDE;
    if (r < 60) atomicAdd(&shadow[half * 64 + r], (double)v[0]);

    // ---- last-block finish (threadfence-reduction protocol) ----
    __syncthreads();                 // drains vmcnt(0): ALL this block's shadow
                                     // atomics are complete before tid 0 signals
    __shared__ int is_last;
    if (tid == 0) {
        __threadfence();             // release
        unsigned prev = __hip_atomic_fetch_add(ctr, 1u, __ATOMIC_ACQ_REL,
                                               __HIP_MEMORY_SCOPE_AGENT);
        is_last = (prev == (unsigned)gridDim.x - 1u);
    }
    __syncthreads();
    if (!is_last) return;
    __threadfence();                 // acquire: other blocks' shadow atomics visible

    __shared__ double psum[120][2];
    __shared__ float aff[256];
    if (tid < 240) {
        const int pair = tid >> 1, sub = tid & 1;
        const int slot = (pair < 60) ? pair : pair + 4;
        double s = 0.0;
#pragma unroll
        for (int c = 0; c < 8; ++c)
            s += __hip_atomic_load(&acc[(size_t)(sub * 8 + c) * SLOT_STRIDE + slot],
                                   __ATOMIC_RELAXED, __HIP_MEMORY_SCOPE_AGENT);
        psum[pair][sub] = s;
    }
    __syncthreads();
    {
        const int a = tid >> 4, b = tid & 15;
        if (a < b) {
            const int k = 15 * a - (a * (a - 1)) / 2 + (b - a - 1);
            float vv = (float)((psum[k][0] + psum[k][1]) * (1.0 / D_TOTAL));
            aff[a * 16 + b] = vv;
            aff[b * 16 + a] = vv;
        } else if (a == b) {
            aff[tid] = 1.0f;         // mean(exp(0)) == 1 exactly
        }
    }
    __syncthreads();
    if (tid < 16) {
        const float* row = &aff[tid * 16];
        float v1 = 1e30f; int i1 = -1;
        for (int j = 0; j < 16; ++j) {
            float x = row[j];
            if (x < v1) { v1 = x; i1 = j; }
        }
        float v2 = 1e30f; int i2 = -1;
        for (int j = 0; j < 16; ++j) {
            if (j == i1) continue;
            float x = row[j];
            if (x < v2) { v2 = x; i2 = j; }
        }
        for (int j = 0; j < 16; ++j)
            out[tid * 16 + j] = (j == i1 || j == i2) ? 0.0f : row[j];
    }
}

// ============================ fallback (round-1, verified) ============================

#define NPAIR_SLOTS_FB 256
#define NSHADOW_FB 8

__global__ __launch_bounds__(64) void pm_accum_fb(const float* __restrict__ in,
                                                  double* __restrict__ acc) {
    const int blk = blockIdx.x;
    const int hh  = blk & 63;
    const int img = blk >> 6;
    const int ww  = threadIdx.x;

    const float* base = in + (size_t)img * IMG_STRIDE;
    float P[16];
#pragma unroll
    for (int n = 0; n < 4; ++n) {
        const float* r0 = base + (size_t)(10 * (n * 64 + hh) + 4) * W_IN;
#pragma unroll
        for (int m = 0; m < 4; ++m) {
            const int col = 10 * (m * 64 + ww) + 4;
            float2 t = *reinterpret_cast<const float2*>(r0 + col);
            float2 u = *reinterpret_cast<const float2*>(r0 + W_IN + col);
            P[n * 4 + m] = 0.25f * ((t.x + t.y) + (u.x + u.y));
        }
    }
    double* shadow = acc + (size_t)(blk & (NSHADOW_FB - 1)) * NPAIR_SLOTS_FB;
    int k = 0;
#pragma unroll
    for (int a = 0; a < 16; ++a)
#pragma unroll
        for (int b = a + 1; b < 16; ++b) {
            float dd = P[a] - P[b];
            float vv = __expf(-dd * dd);
#pragma unroll
            for (int s = 32; s >= 1; s >>= 1) vv += __shfl_xor(vv, s, 64);
            if (ww == (k & 63)) atomicAdd(&shadow[a * 16 + b], (double)vv);
            ++k;
        }
}

__global__ __launch_bounds__(256) void pm_finish_fb(const double* __restrict__ acc,
                                                    float* __restrict__ out) {
    __shared__ float aff[256];
    const int tid = threadIdx.x;
    const int a = tid >> 4, b = tid & 15;
    if (a < b) {
        double s = 0.0;
#pragma unroll
        for (int c = 0; c < NSHADOW_FB; ++c) s += acc[c * NPAIR_SLOTS_FB + tid];
        float vv = (float)(s * (1.0 / D_TOTAL));
        aff[a * 16 + b] = vv;
        aff[b * 16 + a] = vv;
    } else if (a == b) {
        aff[tid] = 1.0f;
    }
    __syncthreads();
    if (tid < 16) {
        const float* row = &aff[tid * 16];
        float v1 = 1e30f; int i1 = -1;
        for (int j = 0; j < 16; ++j) {
            float x = row[j];
            if (x < v1) { v1 = x; i1 = j; }
        }
        float v2 = 1e30f; int i2 = -1;
        for (int j = 0; j < 16; ++j) {
            if (j == i1) continue;
            float x = row[j];
            if (x < v2) { v2 = x; i2 = j; }
        }
        for (int j = 0; j < 16; ++j)
            out[tid * 16 + j] = (j == i1 || j == i2) ? 0.0f : row[j];
    }
}

// ============================ launch ============================

extern "C" void kernel_launch(void* const* d_in, const int* in_sizes, int n_in,
                              void* d_out, int out_size, void* d_ws, size_t ws_size,
                              hipStream_t stream) {
    const float* in = (const float*)d_in[0];
    float* out = (float*)d_out;

    if (ws_size >= (size_t)WS_NEEDED) {
        double* acc = (double*)d_ws;
        unsigned int* wsu = (unsigned int*)d_ws;
        float* Pm = (float*)((char*)d_ws + PMAT_OFF);
        pm_resize<<<dim3(6144), dim3(256), 0, stream>>>(in, Pm, wsu);
        pm_pairs<<<dim3(768), dim3(256), 0, stream>>>(Pm, acc, wsu + CTR_OFF_U32, out);
    } else {
        double* acc = (double*)d_ws;
        hipMemsetAsync(d_ws, 0, NSHADOW_FB * NPAIR_SLOTS_FB * sizeof(double), stream);
        pm_accum_fb<<<dim3(1536), dim3(64), 0, stream>>>(in, acc);
        pm_finish_fb<<<dim3(1), dim3(256), 0, stream>>>(acc, out);
    }
}

// Round 7
// 52.610 us; speedup vs baseline: 1.8076x; 1.8076x over previous
//
#include <hip/hip_runtime.h>

// PatchManifold: bilinear 10x downsample (align_corners=False, scale 10 ->
// frac == 0.5 exactly -> resized pixel = mean of 2x2 input block at rows
// 10i+4,10i+5 / cols 10j+4,10j+5), 16x16 pairwise patch affinity
// mean_d(exp(-(Pa-Pb)^2)), diag == 1, zero 2 smallest per row (stable
// first-index tie-break == jnp.argsort take-k).
//
// Input : d_in[0] = targets f32 [8,3,2560,2560]
// Output: d_out   = f32 [16,16]
//
// R5 -> R6: ONE change. R5's pair-fill indexed v[] with runtime `half`
// (tid>>7) -> v[64] went to scratch (rule #20), ~300 MB of scratch traffic
// ~= the +55us regression. Fix: template<int HALF> so every v[] index is
// compile-time; wave-uniform branch selects the instantiation.
// (R6 bench was lost to an unresponsive container; resubmitting verbatim.)
//
// 2 dispatches:
//   K1 pm_resize <<<6144,256>>>: P_mat[16][98304] f32 -> ws; blocks 0..15
//      zero the 16KB shadow region, block 16 zeroes the last-block counter.
//   K2 pm_pairs  <<<768,256>>> : 2 threads/column (60 pairs each), 63-shfl
//      transposed butterfly, f64 device-scope atomics into 16 shadows; then
//      threadfence-reduction last-block finish (protocol validated in R5):
//        atomics -> __syncthreads -> release fence -> ACQ_REL ctr inc ->
//        broadcast -> acquire fence -> AGENT loads -> mean/mask/write.

#define W_IN 2560
#define IMG_STRIDE (2560 * 2560)
#define D_TOTAL_I 98304
#define D_TOTAL 98304.0

#define NSHADOW 16
#define SLOT_STRIDE 128
#define SHADOW_BYTES (NSHADOW * SLOT_STRIDE * 8)   // 16 KiB
#define CTR_OFF_U32 (SHADOW_BYTES / 4)             // u32 index of counter
#define PMAT_OFF 65536
#define WS_NEEDED (PMAT_OFF + 16 * D_TOTAL_I * 4)

// ============================ K1: resize ============================

__global__ __launch_bounds__(256) void pm_resize(const float* __restrict__ in,
                                                 float* __restrict__ Pm,
                                                 unsigned int* __restrict__ wsu) {
    const int blk = blockIdx.x;            // img*256 + hh*4 + n   (6144 blocks)
    const int tid = threadIdx.x;

    // zero shadow accumulators (16KB) + last-block counter
    if (blk < 16) wsu[blk * 256 + tid] = 0u;
    else if (blk == 16 && tid == 0) wsu[CTR_OFF_U32] = 0u;

    const int n   = blk & 3;
    const int hh  = (blk >> 2) & 63;
    const int img = blk >> 8;
    const int m   = tid >> 6;
    const int ww  = tid & 63;

    const float* r0 = in + (size_t)img * IMG_STRIDE
                         + (size_t)(640 * n + 10 * hh + 4) * W_IN
                         + (640 * m + 10 * ww + 4);
    float2 t = *reinterpret_cast<const float2*>(r0);
    float2 u = *reinterpret_cast<const float2*>(r0 + W_IN);
    Pm[(size_t)(n * 4 + m) * D_TOTAL_I + img * 4096 + hh * 64 + ww] =
        0.25f * ((t.x + t.y) + (u.x + u.y));
}

// ============================ K2: pairs + finish ============================

// Compile-time HALF keeps every v[] index constant -> v stays in VGPRs.
template <int HALF>
__device__ __forceinline__ void pm_fill(const float* __restrict__ P,
                                        float* __restrict__ v) {
    int k = 0;
#pragma unroll
    for (int a = 0; a < 16; ++a)
#pragma unroll
        for (int b = a + 1; b < 16; ++b) {
            if (k >= HALF * 60 && k < HALF * 60 + 60) {
                float df = P[a] - P[b];
                v[k - HALF * 60] = __expf(-df * df);
            }
            ++k;
        }
}

__global__ __launch_bounds__(256) void pm_pairs(const float* __restrict__ Pm,
                                                double* __restrict__ acc,
                                                unsigned int* __restrict__ ctr,
                                                float* __restrict__ out) {
    const int tid  = threadIdx.x;
    const int lane = tid & 63;
    const int half = tid >> 7;                 // waves 0-1: pairs 0..59, 2-3: 60..119
    const int d    = blockIdx.x * 128 + (tid & 127);

    float P[16];
#pragma unroll
    for (int p = 0; p < 16; ++p) P[p] = Pm[p * D_TOTAL_I + d];

    float v[64];
    if (half == 0) pm_fill<0>(P, v);           // wave-uniform branch
    else           pm_fill<1>(P, v);
    v[60] = 0.0f; v[61] = 0.0f; v[62] = 0.0f; v[63] = 0.0f;

    // 6-stage transposed butterfly (verified R3): lane ends owning slot
    // bitrev6(lane), fully wave-summed.
#define PM_STAGE(K, H)                                         \
    {                                                          \
        const bool bit = (lane >> (K)) & 1;                    \
        _Pragma("unroll")                                      \
        for (int i = 0; i < (H); ++i) {                        \
            float keep = bit ? v[i + (H)] : v[i];              \
            float send = bit ? v[i] : v[i + (H)];              \
            v[i] = keep + __shfl_xor(send, 1 << (K), 64);      \
        }                                                      \
    }
    PM_STAGE(0, 32)
    PM_STAGE(1, 16)
    PM_STAGE(2, 8)
    PM_STAGE(3, 4)
    PM_STAGE(4, 2)
    PM_STAGE(5, 1)
#undef PM_STAGE

    const int r = __brev(lane) >> 26;
    double* shadow = acc + (size_t)(blockIdx.x & (NSHADOW - 1)) * SLOT_STRIDE;
    if (r < 60) atomicAdd(&shadow[half * 64 + r], (double)v[0]);

    // ---- last-block finish (threadfence-reduction protocol, validated R5) ----
    __syncthreads();                 // all this block's shadow atomics issued+drained
    __shared__ int is_last;
    if (tid == 0) {
        __threadfence();             // release
        unsigned prev = __hip_atomic_fetch_add(ctr, 1u, __ATOMIC_ACQ_REL,
                                               __HIP_MEMORY_SCOPE_AGENT);
        is_last = (prev == (unsigned)gridDim.x - 1u);
    }
    __syncthreads();
    if (!is_last) return;
    __threadfence();                 // acquire

    __shared__ double psum[120][2];
    __shared__ float aff[256];
    if (tid < 240) {
        const int pair = tid >> 1, sub = tid & 1;
        const int slot = (pair < 60) ? pair : pair + 4;
        double s = 0.0;
#pragma unroll
        for (int c = 0; c < 8; ++c)
            s += __hip_atomic_load(&acc[(size_t)(sub * 8 + c) * SLOT_STRIDE + slot],
                                   __ATOMIC_RELAXED, __HIP_MEMORY_SCOPE_AGENT);
        psum[pair][sub] = s;
    }
    __syncthreads();
    {
        const int a = tid >> 4, b = tid & 15;
        if (a < b) {
            const int k = 15 * a - (a * (a - 1)) / 2 + (b - a - 1);
            float vv = (float)((psum[k][0] + psum[k][1]) * (1.0 / D_TOTAL));
            aff[a * 16 + b] = vv;
            aff[b * 16 + a] = vv;
        } else if (a == b) {
            aff[tid] = 1.0f;         // mean(exp(0)) == 1 exactly
        }
    }
    __syncthreads();
    if (tid < 16) {
        const float* row = &aff[tid * 16];
        float v1 = 1e30f; int i1 = -1;
        for (int j = 0; j < 16; ++j) {
            float x = row[j];
            if (x < v1) { v1 = x; i1 = j; }
        }
        float v2 = 1e30f; int i2 = -1;
        for (int j = 0; j < 16; ++j) {
            if (j == i1) continue;
            float x = row[j];
            if (x < v2) { v2 = x; i2 = j; }
        }
        for (int j = 0; j < 16; ++j)
            out[tid * 16 + j] = (j == i1 || j == i2) ? 0.0f : row[j];
    }
}

// ============================ fallback (round-1, verified) ============================

#define NPAIR_SLOTS_FB 256
#define NSHADOW_FB 8

__global__ __launch_bounds__(64) void pm_accum_fb(const float* __restrict__ in,
                                                  double* __restrict__ acc) {
    const int blk = blockIdx.x;
    const int hh  = blk & 63;
    const int img = blk >> 6;
    const int ww  = threadIdx.x;

    const float* base = in + (size_t)img * IMG_STRIDE;
    float P[16];
#pragma unroll
    for (int n = 0; n < 4; ++n) {
        const float* r0 = base + (size_t)(10 * (n * 64 + hh) + 4) * W_IN;
#pragma unroll
        for (int m = 0; m < 4; ++m) {
            const int col = 10 * (m * 64 + ww) + 4;
            float2 t = *reinterpret_cast<const float2*>(r0 + col);
            float2 u = *reinterpret_cast<const float2*>(r0 + W_IN + col);
            P[n * 4 + m] = 0.25f * ((t.x + t.y) + (u.x + u.y));
        }
    }
    double* shadow = acc + (size_t)(blk & (NSHADOW_FB - 1)) * NPAIR_SLOTS_FB;
    int k = 0;
#pragma unroll
    for (int a = 0; a < 16; ++a)
#pragma unroll
        for (int b = a + 1; b < 16; ++b) {
            float dd = P[a] - P[b];
            float vv = __expf(-dd * dd);
#pragma unroll
            for (int s = 32; s >= 1; s >>= 1) vv += __shfl_xor(vv, s, 64);
            if (ww == (k & 63)) atomicAdd(&shadow[a * 16 + b], (double)vv);
            ++k;
        }
}

__global__ __launch_bounds__(256) void pm_finish_fb(const double* __restrict__ acc,
                                                    float* __restrict__ out) {
    __shared__ float aff[256];
    const int tid = threadIdx.x;
    const int a = tid >> 4, b = tid & 15;
    if (a < b) {
        double s = 0.0;
#pragma unroll
        for (int c = 0; c < NSHADOW_FB; ++c) s += acc[c * NPAIR_SLOTS_FB + tid];
        float vv = (float)(s * (1.0 / D_TOTAL));
        aff[a * 16 + b] = vv;
        aff[b * 16 + a] = vv;
    } else if (a == b) {
        aff[tid] = 1.0f;
    }
    __syncthreads();
    if (tid < 16) {
        const float* row = &aff[tid * 16];
        float v1 = 1e30f; int i1 = -1;
        for (int j = 0; j < 16; ++j) {
            float x = row[j];
            if (x < v1) { v1 = x; i1 = j; }
        }
        float v2 = 1e30f; int i2 = -1;
        for (int j = 0; j < 16; ++j) {
            if (j == i1) continue;
            float x = row[j];
            if (x < v2) { v2 = x; i2 = j; }
        }
        for (int j = 0; j < 16; ++j)
            out[tid * 16 + j] = (j == i1 || j == i2) ? 0.0f : row[j];
    }
}

// ============================ launch ============================

extern "C" void kernel_launch(void* const* d_in, const int* in_sizes, int n_in,
                              void* d_out, int out_size, void* d_ws, size_t ws_size,
                              hipStream_t stream) {
    const float* in = (const float*)d_in[0];
    float* out = (float*)d_out;

    if (ws_size >= (size_t)WS_NEEDED) {
        double* acc = (double*)d_ws;
        unsigned int* wsu = (unsigned int*)d_ws;
        float* Pm = (float*)((char*)d_ws + PMAT_OFF);
        pm_resize<<<dim3(6144), dim3(256), 0, stream>>>(in, Pm, wsu);
        pm_pairs<<<dim3(768), dim3(256), 0, stream>>>(Pm, acc, wsu + CTR_OFF_U32, out);
    } else {
        double* acc = (double*)d_ws;
        hipMemsetAsync(d_ws, 0, NSHADOW_FB * NPAIR_SLOTS_FB * sizeof(double), stream);
        pm_accum_fb<<<dim3(1536), dim3(64), 0, stream>>>(in, acc);
        pm_finish_fb<<<dim3(1), dim3(256), 0, stream>>>(acc, out);
    }
}

// Round 8
// 32.753 us; speedup vs baseline: 2.9036x; 1.6063x over previous
//
#include <hip/hip_runtime.h>

// PatchManifold: bilinear 10x downsample (align_corners=False, scale 10 ->
// frac == 0.5 exactly -> resized pixel = mean of 2x2 input block at rows
// 10i+4,10i+5 / cols 10j+4,10j+5), 16x16 pairwise patch affinity
// mean_d(exp(-(Pa-Pb)^2)), diag == 1, zero 2 smallest per row (stable
// first-index tie-break == jnp.argsort take-k).
//
// Input : d_in[0] = targets f32 [8,3,2560,2560]
// Output: d_out   = f32 [16,16]
//
// R7 -> R8 (two changes, both counter-motivated):
//  1. Resize fetch was 40B-strided float2 (eff ~3.6 TB/s). Rows 10i+4 and
//     10i+5 are ADJACENT -> each (img,i) is one contiguous 20KB chunk.
//     K1 now streams the chunk with float4 loads into LDS and extracts the
//     512 needed columns from LDS: pure sequential-burst HBM (~6.5 TB/s).
//  2. R7's last-block finish cost ~13us: agent-scope __threadfence on
//     gfx950 = buffer_wbl2/buffer_inv (L2 writeback/inv) PER BLOCK x768 +
//     serialized cross-XCD counter RMWs. Dropped entirely; ordering comes
//     from kernel boundaries again (R2 structure): separate 1-block finish.
//
// 3 dispatches:
//   K1 pm_resize_stream <<<6144,256>>>: blocks 0..15 also zero the 16KB
//      shadow region. LDS-stage 20KB chunk, write P_mat[16][98304].
//   K2 pm_pairs <<<768,256>>>: 2 threads/column (60 pairs each, template
//      fill keeps v[] in VGPRs - rule #20), 63-shfl transposed butterfly,
//      one f64 atomicAdd per thread-slot into 16 shadows. No fences.
//   K3 pm_finish <<<1,256>>>: sum shadows, mean, mirror, mask, write.

#define W_IN 2560
#define IMG_STRIDE (2560 * 2560)
#define D_TOTAL_I 98304
#define D_TOTAL 98304.0

#define NSHADOW 16
#define SLOT_STRIDE 128
#define SHADOW_BYTES (NSHADOW * SLOT_STRIDE * 8)   // 16 KiB
#define PMAT_OFF 65536
#define WS_NEEDED (PMAT_OFF + 16 * D_TOTAL_I * 4)

// ============================ K1: streaming resize ============================

__global__ __launch_bounds__(256) void pm_resize_stream(const float* __restrict__ in,
                                                        float* __restrict__ Pm,
                                                        unsigned int* __restrict__ wsu) {
    const int blk = blockIdx.x;            // img*256 + i   (6144 blocks)
    const int tid = threadIdx.x;

    // zero the 16KB shadow region (kernel boundary orders it before K2)
    if (blk < 16) wsu[blk * 256 + tid] = 0u;

    const int i   = blk & 255;             // resized row 0..255
    const int img = blk >> 8;

    // rows 10i+4 and 10i+5: one contiguous 20KB chunk -> LDS
    __shared__ float rows[2 * W_IN];
    const float4* s4 = reinterpret_cast<const float4*>(
        in + (size_t)img * IMG_STRIDE + (size_t)(10 * i + 4) * W_IN);
    float4* l4 = reinterpret_cast<float4*>(rows);
#pragma unroll
    for (int q = 0; q < 5; ++q) l4[q * 256 + tid] = s4[q * 256 + tid];
    __syncthreads();

    // thread = output col j: 2x2 average from LDS
    const int j = tid;
    float a = rows[10 * j + 4], b = rows[10 * j + 5];
    float c = rows[W_IN + 10 * j + 4], d = rows[W_IN + 10 * j + 5];
    const int n = i >> 6, hh = i & 63;
    const int m = j >> 6, ww = j & 63;
    Pm[(size_t)(n * 4 + m) * D_TOTAL_I + img * 4096 + hh * 64 + ww] =
        0.25f * ((a + b) + (c + d));
}

// ============================ K2: pairs ============================

// Compile-time HALF keeps every v[] index constant -> v stays in VGPRs.
template <int HALF>
__device__ __forceinline__ void pm_fill(const float* __restrict__ P,
                                        float* __restrict__ v) {
    int k = 0;
#pragma unroll
    for (int a = 0; a < 16; ++a)
#pragma unroll
        for (int b = a + 1; b < 16; ++b) {
            if (k >= HALF * 60 && k < HALF * 60 + 60) {
                float df = P[a] - P[b];
                v[k - HALF * 60] = __expf(-df * df);
            }
            ++k;
        }
}

__global__ __launch_bounds__(256) void pm_pairs(const float* __restrict__ Pm,
                                                double* __restrict__ acc) {
    const int tid  = threadIdx.x;
    const int lane = tid & 63;
    const int half = tid >> 7;                 // waves 0-1: pairs 0..59, 2-3: 60..119
    const int d    = blockIdx.x * 128 + (tid & 127);

    float P[16];
#pragma unroll
    for (int p = 0; p < 16; ++p) P[p] = Pm[p * D_TOTAL_I + d];

    float v[64];
    if (half == 0) pm_fill<0>(P, v);           // wave-uniform branch
    else           pm_fill<1>(P, v);
    v[60] = 0.0f; v[61] = 0.0f; v[62] = 0.0f; v[63] = 0.0f;

    // 6-stage transposed butterfly: lane ends owning slot bitrev6(lane),
    // fully wave-summed (verified R3/R7).
#define PM_STAGE(K, H)                                         \
    {                                                          \
        const bool bit = (lane >> (K)) & 1;                    \
        _Pragma("unroll")                                      \
        for (int i = 0; i < (H); ++i) {                        \
            float keep = bit ? v[i + (H)] : v[i];              \
            float send = bit ? v[i] : v[i + (H)];              \
            v[i] = keep + __shfl_xor(send, 1 << (K), 64);      \
        }                                                      \
    }
    PM_STAGE(0, 32)
    PM_STAGE(1, 16)
    PM_STAGE(2, 8)
    PM_STAGE(3, 4)
    PM_STAGE(4, 2)
    PM_STAGE(5, 1)
#undef PM_STAGE

    const int r = __brev(lane) >> 26;
    double* shadow = acc + (size_t)(blockIdx.x & (NSHADOW - 1)) * SLOT_STRIDE;
    if (r < 60) atomicAdd(&shadow[half * 64 + r], (double)v[0]);
}

// ============================ K3: finish ============================

__global__ __launch_bounds__(256) void pm_finish(const double* __restrict__ acc,
                                                 float* __restrict__ out) {
    __shared__ float aff[256];
    const int tid = threadIdx.x;
    const int a = tid >> 4, b = tid & 15;
    if (a < b) {
        const int k = 15 * a - (a * (a - 1)) / 2 + (b - a - 1);  // pair idx
        const int slot = (k < 60) ? k : k + 4;                   // half1 at 64+
        double s = 0.0;
#pragma unroll
        for (int c = 0; c < NSHADOW; ++c) s += acc[c * SLOT_STRIDE + slot];
        float vv = (float)(s * (1.0 / D_TOTAL));
        aff[a * 16 + b] = vv;
        aff[b * 16 + a] = vv;
    } else if (a == b) {
        aff[tid] = 1.0f;             // mean(exp(0)) == 1 exactly
    }
    __syncthreads();
    if (tid < 16) {
        const float* row = &aff[tid * 16];
        float v1 = 1e30f; int i1 = -1;
        for (int j = 0; j < 16; ++j) {
            float x = row[j];
            if (x < v1) { v1 = x; i1 = j; }
        }
        float v2 = 1e30f; int i2 = -1;
        for (int j = 0; j < 16; ++j) {
            if (j == i1) continue;
            float x = row[j];
            if (x < v2) { v2 = x; i2 = j; }
        }
        for (int j = 0; j < 16; ++j)
            out[tid * 16 + j] = (j == i1 || j == i2) ? 0.0f : row[j];
    }
}

// ============================ fallback (round-1, verified) ============================

#define NPAIR_SLOTS_FB 256
#define NSHADOW_FB 8

__global__ __launch_bounds__(64) void pm_accum_fb(const float* __restrict__ in,
                                                  double* __restrict__ acc) {
    const int blk = blockIdx.x;
    const int hh  = blk & 63;
    const int img = blk >> 6;
    const int ww  = threadIdx.x;

    const float* base = in + (size_t)img * IMG_STRIDE;
    float P[16];
#pragma unroll
    for (int n = 0; n < 4; ++n) {
        const float* r0 = base + (size_t)(10 * (n * 64 + hh) + 4) * W_IN;
#pragma unroll
        for (int m = 0; m < 4; ++m) {
            const int col = 10 * (m * 64 + ww) + 4;
            float2 t = *reinterpret_cast<const float2*>(r0 + col);
            float2 u = *reinterpret_cast<const float2*>(r0 + W_IN + col);
            P[n * 4 + m] = 0.25f * ((t.x + t.y) + (u.x + u.y));
        }
    }
    double* shadow = acc + (size_t)(blk & (NSHADOW_FB - 1)) * NPAIR_SLOTS_FB;
    int k = 0;
#pragma unroll
    for (int a = 0; a < 16; ++a)
#pragma unroll
        for (int b = a + 1; b < 16; ++b) {
            float dd = P[a] - P[b];
            float vv = __expf(-dd * dd);
#pragma unroll
            for (int s = 32; s >= 1; s >>= 1) vv += __shfl_xor(vv, s, 64);
            if (ww == (k & 63)) atomicAdd(&shadow[a * 16 + b], (double)vv);
            ++k;
        }
}

__global__ __launch_bounds__(256) void pm_finish_fb(const double* __restrict__ acc,
                                                    float* __restrict__ out) {
    __shared__ float aff[256];
    const int tid = threadIdx.x;
    const int a = tid >> 4, b = tid & 15;
    if (a < b) {
        double s = 0.0;
#pragma unroll
        for (int c = 0; c < NSHADOW_FB; ++c) s += acc[c * NPAIR_SLOTS_FB + tid];
        float vv = (float)(s * (1.0 / D_TOTAL));
        aff[a * 16 + b] = vv;
        aff[b * 16 + a] = vv;
    } else if (a == b) {
        aff[tid] = 1.0f;
    }
    __syncthreads();
    if (tid < 16) {
        const float* row = &aff[tid * 16];
        float v1 = 1e30f; int i1 = -1;
        for (int j = 0; j < 16; ++j) {
            float x = row[j];
            if (x < v1) { v1 = x; i1 = j; }
        }
        float v2 = 1e30f; int i2 = -1;
        for (int j = 0; j < 16; ++j) {
            if (j == i1) continue;
            float x = row[j];
            if (x < v2) { v2 = x; i2 = j; }
        }
        for (int j = 0; j < 16; ++j)
            out[tid * 16 + j] = (j == i1 || j == i2) ? 0.0f : row[j];
    }
}

// ============================ launch ============================

extern "C" void kernel_launch(void* const* d_in, const int* in_sizes, int n_in,
                              void* d_out, int out_size, void* d_ws, size_t ws_size,
                              hipStream_t stream) {
    const float* in = (const float*)d_in[0];
    float* out = (float*)d_out;

    if (ws_size >= (size_t)WS_NEEDED) {
        double* acc = (double*)d_ws;
        unsigned int* wsu = (unsigned int*)d_ws;
        float* Pm = (float*)((char*)d_ws + PMAT_OFF);
        pm_resize_stream<<<dim3(6144), dim3(256), 0, stream>>>(in, Pm, wsu);
        pm_pairs<<<dim3(768), dim3(256), 0, stream>>>(Pm, acc);
        pm_finish<<<dim3(1), dim3(256), 0, stream>>>(acc, out);
    } else {
        double* acc = (double*)d_ws;
        hipMemsetAsync(d_ws, 0, NSHADOW_FB * NPAIR_SLOTS_FB * sizeof(double), stream);
        pm_accum_fb<<<dim3(1536), dim3(64), 0, stream>>>(in, acc);
        pm_finish_fb<<<dim3(1), dim3(256), 0, stream>>>(acc, out);
    }
}